// Round 1
// baseline (465.600 us; speedup 1.0000x reference)
//
#include <hip/hip_runtime.h>

#define NTAG 128
#define SEQ 512
#define NBATCH 512
#define END_ID 1

typedef _Float16 h2 __attribute__((ext_vector_type(2)));
typedef __fp16 fp16x2 __attribute__((ext_vector_type(2)));

#define LOG2E 1.4426950408889634f
#define LN2   0.6931471805599453f

__device__ __forceinline__ uint pack2(float a, float b) {
  fp16x2 h = __builtin_amdgcn_cvt_pkrtz(a, b);
  return __builtin_bit_cast(uint, h);
}
__device__ __forceinline__ h2 as_h2(uint u) { return __builtin_bit_cast(h2, u); }

__device__ __forceinline__ float fast_exp2(float x) {
#if __has_builtin(__builtin_amdgcn_exp2f)
  return __builtin_amdgcn_exp2f(x);
#else
  return exp2f(x);
#endif
}
__device__ __forceinline__ float fast_log2(float x) {
#if __has_builtin(__builtin_amdgcn_logf)
  return __builtin_amdgcn_logf(x);
#else
  return log2f(x);
#endif
}

#if __has_builtin(__builtin_amdgcn_fdot2)
#define FDOT2(pu, eu, acc) acc = __builtin_amdgcn_fdot2(as_h2(pu), as_h2(eu), acc, false)
#else
#define FDOT2(pu, eu, acc) do { h2 _p = as_h2(pu), _e = as_h2(eu); \
  acc = fmaf((float)_p.x, (float)_e.x, fmaf((float)_p.y, (float)_e.y, acc)); } while (0)
#endif

#define RL(v, l) ((uint)__builtin_amdgcn_readlane((int)(v), (l)))

// ROUND-9 KEY CHANGE: 2 waves per batch (128-thread block), ONE tag per lane,
// full K=128 per lane. E' shrinks to 64 u32/lane -> stays in arch VGPRs (the
// old 2-tag/lane layout needed 128 u32 and spilled E' to AGPRs: VGPR_Count=88
// with ~128 v_accvgpr_read per step on the critical chain). Cross-wave p
// exchange via double-buffered f32 LDS (1 barrier/step). The per-step
// log-domain renorm (exp2/log2 of alpha + M broadcast) is replaced by a
// LINEAR-domain recurrence: p_{t+1}[j] = (sum_k p[k]*2^{-c}*E'[j][k]) * e^{x_t[j]},
// with c = floor(log2 p[0]) derived bit-identically in every lane from a
// broadcast LDS read; alpha[j] = M + log2(p[j]) reconstructed once at the end.
// f32 p has huge headroom (per-step growth <= ~2^33), and the f16-packed dot
// operands (p * 2^{-c}) stay within f16 range exactly like the old kernel.
__global__ __launch_bounds__(128) void crf_kernel(
    const float* __restrict__ x,      // [B,S,T]
    const int*   __restrict__ tags,   // [B,S]
    const float* __restrict__ mask,   // [B,S]
    const float* __restrict__ trans,  // [T,T]
    float* __restrict__ ws)           // [B]
{
  const int b   = blockIdx.x;
  const int tid = threadIdx.x;
  const int w   = tid >> 6;          // wave 0..1
  const int l   = tid & 63;          // lane
  const int j   = (w << 6) + l;      // owned tag 0..127

  __shared__ float pbuf[2][NTAG];    // double-buffered p (f32)
  __shared__ float vbuf[NTAG];       // final alpha_ln for epilogue

  const float* xb   = x    + (size_t)b * SEQ * NTAG;
  const float* mrow = mask + (size_t)b * SEQ;
  const int*   trow = tags + (size_t)b * SEQ;

  // ---- len = sum(mask row); exact 0/1, monotonic (each wave redundantly) ----
  float msum = 0.f;
  #pragma unroll
  for (int i = 0; i < SEQ / 64; ++i) msum += mrow[l + i * 64];
  #pragma unroll
  for (int off = 1; off < 64; off <<= 1) msum += __shfl_xor(msum, off);
  const int len = (int)msum;          // in [1, 510]

  // ---- E' row j: exp(trans[j][k]) packed f16 pairs, 64 u32 (arch VGPRs) ----
  uint e[64];
  {
    const float4* tr = (const float4*)(trans + (size_t)j * NTAG);
    #pragma unroll
    for (int k4 = 0; k4 < 32; ++k4) {
      float4 t4 = tr[k4];
      e[2 * k4 + 0] = pack2(fast_exp2(t4.x * LOG2E), fast_exp2(t4.y * LOG2E));
      e[2 * k4 + 1] = pack2(fast_exp2(t4.z * LOG2E), fast_exp2(t4.w * LOG2E));
    }
  }

  // ---- init: p0 = delta(START_ID=0), M = 0 (alpha = M + log2 p) ----
  float pcur = (j == 0) ? 1.f : 0.f;
  float M = 0.f;
  pbuf[0][j] = pcur;
  __syncthreads();

  // x prefetch, depth 4 (rows 0..3 always in-bounds: SEQ=512)
  const float* xj = xb + j;          // row g: xj[g*NTAG]
  float xf0 = xj[0 * NTAG];
  float xf1 = xj[1 * NTAG];
  float xf2 = xj[2 * NTAG];
  float xf3 = xj[3 * NTAG];

#define CRF_STEP(XF, S_)                                                      \
  {                                                                           \
    const int g  = t + (S_);                                                  \
    const int rs = (S_) & 1;   /* t is a multiple of 4 */                     \
    const float exv = fast_exp2(XF * LOG2E);  /* e^{x_t[j]} */                \
    XF = xj[(size_t)min(g + 4, len) * NTAG];  /* refill, 4 in flight */       \
    const float2 pp = ((const float2*)pbuf[rs])[l];  /* pair (2l, 2l+1) */    \
    const float  p0 = pbuf[rs][0];                   /* broadcast read */     \
    int c = ((__float_as_int(p0) >> 23) & 0xff) - 127;                        \
    c = c < -60 ? -60 : (c > 60 ? 60 : c);                                    \
    const float sc = __int_as_float((127 - c) << 23);   /* 2^{-c} */          \
    const uint pk = pack2(fminf(pp.x * sc, 60000.f),                          \
                          fminf(pp.y * sc, 60000.f));                         \
    float q0 = 0.f, q1 = 0.f, q2 = 0.f, q3 = 0.f;                             \
    _Pragma("unroll")                                                         \
    for (int gg = 0; gg < 64; gg += 8) {                                      \
      const uint s0 = RL(pk, gg + 0), s1 = RL(pk, gg + 1);                    \
      const uint s2 = RL(pk, gg + 2), s3 = RL(pk, gg + 3);                    \
      const uint s4 = RL(pk, gg + 4), s5 = RL(pk, gg + 5);                    \
      const uint s6 = RL(pk, gg + 6), s7 = RL(pk, gg + 7);                    \
      FDOT2(s0, e[gg + 0], q0); FDOT2(s1, e[gg + 1], q1);                     \
      FDOT2(s2, e[gg + 2], q2); FDOT2(s3, e[gg + 3], q3);                     \
      FDOT2(s4, e[gg + 4], q0); FDOT2(s5, e[gg + 5], q1);                     \
      FDOT2(s6, e[gg + 6], q2); FDOT2(s7, e[gg + 7], q3);                     \
    }                                                                         \
    const float q  = (q0 + q1) + (q2 + q3);                                   \
    const float pn = q * exv;                                                 \
    const bool act = (g < len);                                               \
    pcur = act ? pn : pcur;                                                   \
    M    = act ? (M + (float)c) : M;                                          \
    pbuf[rs ^ 1][j] = pcur;                                                   \
    __syncthreads();                                                          \
  }

  for (int t = 0; t < len; t += 4) {
    CRF_STEP(xf0, 0)
    CRF_STEP(xf1, 1)
    CRF_STEP(xf2, 2)
    CRF_STEP(xf3, 3)
  }
#undef CRF_STEP

  // ---- alpha back to natural-log domain; one log2 total ----
  const float a_ln = (M + fast_log2(pcur)) * LN2;   // -inf ok for dead tags
  vbuf[j] = a_ln;
  __syncthreads();

  if (w == 0) {
    // ---- fwd = logsumexp_j(alpha[j] + trans[END][j]) ----
    const float2 te = ((const float2*)(trans + END_ID * NTAG))[l];
    const float v_lo = vbuf[2 * l]     + te.x;
    const float v_hi = vbuf[2 * l + 1] + te.y;
    float m2 = fmaxf(v_lo, v_hi);
    #pragma unroll
    for (int off = 1; off < 64; off <<= 1) m2 = fmaxf(m2, __shfl_xor(m2, off));
    float s = fast_exp2((v_lo - m2) * LOG2E) + fast_exp2((v_hi - m2) * LOG2E);
    #pragma unroll
    for (int off = 1; off < 64; off <<= 1) s += __shfl_xor(s, off);
    const float fwd = m2 + fast_log2(s) * LN2;

    // ---- gold score ----
    float gacc = 0.f;
    for (int i = l; i < len; i += 64) {
      const int tn = trow[i + 1];
      const int tp = trow[i];
      gacc += xb[(size_t)i * NTAG + tn] + trans[tn * NTAG + tp];
    }
    #pragma unroll
    for (int off = 1; off < 64; off <<= 1) gacc += __shfl_xor(gacc, off);

    if (l == 0) {
      const float gold = gacc + trans[END_ID * NTAG + trow[len]];
      ws[b] = fwd - gold;
    }
  }
}

__global__ void reduce_kernel(const float* __restrict__ ws, float* __restrict__ out) {
  __shared__ float sm[8];
  const int tid = threadIdx.x;   // 512
  float v = ws[tid];
  #pragma unroll
  for (int off = 1; off < 64; off <<= 1) v += __shfl_xor(v, off);
  if ((tid & 63) == 0) sm[tid >> 6] = v;
  __syncthreads();
  if (tid == 0) {
    float s = 0.f;
    #pragma unroll
    for (int w = 0; w < 8; ++w) s += sm[w];
    out[0] = s * (1.0f / 512.0f);
  }
}

extern "C" void kernel_launch(void* const* d_in, const int* in_sizes, int n_in,
                              void* d_out, int out_size, void* d_ws, size_t ws_size,
                              hipStream_t stream) {
  const float* x     = (const float*)d_in[0];
  const int*   tags  = (const int*)d_in[1];
  const float* mask  = (const float*)d_in[2];
  const float* trans = (const float*)d_in[3];
  float*       ws    = (float*)d_ws;

  crf_kernel<<<NBATCH, 128, 0, stream>>>(x, tags, mask, trans, ws);
  reduce_kernel<<<1, 512, 0, stream>>>(ws, (float*)d_out);
}